// Round 15
// baseline (161.797 us; speedup 1.0000x reference)
//
#include <hip/hip_runtime.h>

#define NNODES 50000
#define NREL   90
#define NEDGE  800000
#define HDIM   16
#define NBASIS 30
#define NCLS   8
#define NPART  392    // partitions = node>>7 ; 0..390 used
#define CH     2048   // edges per pass-1 block (391 blocks)
#define P1BLK  ((NEDGE + CH - 1) / CH)
#define CAPSTG 2816   // fixed staging stride per partition (mean 2046, sigma 45)
#define GS     8      // srcs per msg1 block
#define BSTR2  260    // per-src packed slice stride in u32 (15*16=240 + pad; %4==0)
#define CROW2  20     // packed comp row stride in u32 (15 + pad; %4==0 -> 16B aligned)

typedef __fp16 h2 __attribute__((ext_vector_type(2)));

static __device__ __forceinline__ unsigned pk2(float a, float b) {
    h2 p = __builtin_amdgcn_cvt_pkrtz(a, b);
    return __builtin_bit_cast(unsigned, p);
}
static __device__ __forceinline__ h2 uph(unsigned u) {
    return __builtin_bit_cast(h2, u);
}
static __device__ __forceinline__ float fd2(unsigned a, unsigned b, float c) {
#if __has_builtin(__builtin_amdgcn_fdot2)
    return __builtin_amdgcn_fdot2(uph(a), uph(b), c, false);
#else
    h2 x = uph(a), y = uph(b);
    return fmaf((float)x.y, (float)y.y, fmaf((float)x.x, (float)y.x, c));
#endif
}

// ---------------- parallel inclusive scans in LDS ----------------
__device__ __forceinline__ void scan512_incl(int* sc) {
    int t = threadIdx.x;
#pragma unroll
    for (int d = 1; d < 512; d <<= 1) {
        int v0 = sc[t];
        int a0 = (t >= d) ? sc[t - d] : 0;
        int v1 = sc[t + 256];
        int a1 = sc[t + 256 - d];
        __syncthreads();
        sc[t] = v0 + a0;
        sc[t + 256] = v1 + a1;
        __syncthreads();
    }
}

__device__ __forceinline__ void scan128_incl(int* sc) {
    int t = threadIdx.x;
#pragma unroll
    for (int d = 1; d < 128; d <<= 1) {
        int v = 0, a = 0;
        if (t < 128) { v = sc[t]; a = (t >= d) ? sc[t - d] : 0; }
        __syncthreads();
        if (t < 128) sc[t] = v + a;
        __syncthreads();
    }
}

// ============================================================
// init: cursors, gcnt, pre-packed f16 comp1 rows
// ============================================================
__global__ __launch_bounds__(256) void initc_kernel(int* __restrict__ gcur_s,
                                                    int* __restrict__ gcur_d,
                                                    int* __restrict__ gcnt,
                                                    const float* __restrict__ comp1,
                                                    unsigned* __restrict__ comp_pk) {
    int t = blockIdx.x * 256 + threadIdx.x;
    if (t < NPART) { gcur_s[t] = t * CAPSTG; gcur_d[t] = t * CAPSTG; }
    else if (t == NPART) { gcnt[0] = 0; gcnt[1] = 0; }
    int i = t - 512;
    if (i >= 0 && i < NREL * 15) {
        int r = i / 15;
        int b2 = i - r * 15;
        comp_pk[r * CROW2 + b2] = pk2(comp1[r * NBASIS + 2 * b2],
                                      comp1[r * NBASIS + 2 * b2 + 1]);
    }
    if (i >= NREL * 15 && i < NREL * 15 + NREL * (CROW2 - 15)) {
        int j = i - NREL * 15;
        int r = j / (CROW2 - 15);
        int pcol = 15 + (j - r * (CROW2 - 15));
        comp_pk[r * CROW2 + pcol] = 0;
    }
}

// ============================================================
// dst-sort pass 1: partition raw edges by dst>>7 into fixed-stride staging.
// ============================================================
__global__ __launch_bounds__(256) void p1d_kernel(const int* __restrict__ ei,
                                                  const int* __restrict__ et,
                                                  int* __restrict__ gcur_d,
                                                  int2* __restrict__ stg_d) {
    __shared__ int2 sorted[CH];
    __shared__ int hist[NPART], loff[NPART], cur[NPART], gbase[NPART];
    __shared__ int sc[512];
    int base = blockIdx.x * CH;
    int nitems = min(CH, NEDGE - base);
    int t = threadIdx.x;
    for (int i = t; i < NPART; i += 256) hist[i] = 0;
    __syncthreads();
    for (int i = t; i < nitems; i += 256)
        atomicAdd(&hist[ei[NEDGE + base + i] >> 7], 1);
    __syncthreads();
    sc[t]       = (t < NPART) ? hist[t] : 0;
    sc[t + 256] = (t + 256 < NPART) ? hist[t + 256] : 0;
    __syncthreads();
    scan512_incl(sc);
    for (int p = t; p < NPART; p += 256) {
        int lo = p ? sc[p - 1] : 0;
        loff[p] = lo;
        cur[p] = lo;
        if (hist[p]) gbase[p] = atomicAdd(&gcur_d[p], hist[p]);
    }
    __syncthreads();
    for (int i = t; i < nitems; i += 256) {
        int e = base + i;
        int src = ei[e], dst = ei[NEDGE + e], r = et[e];
        int rk = atomicAdd(&cur[dst >> 7], 1);
        sorted[rk] = make_int2(src | (r << 16), dst);
    }
    __syncthreads();
    for (int s = t; s < nitems; s += 256) {
        int2 it = sorted[s];
        int p = it.y >> 7;
        stg_d[gbase[p] + (s - loff[p])] = it;
    }
}

// ============================================================
// dst-sort pass 2 (+ fused src-partition scatter)
// ============================================================
__global__ __launch_bounds__(256) void p2d_kernel(const int* __restrict__ gcur_d,
                                                  const int2* __restrict__ stg_d,
                                                  int* __restrict__ gcur_s,
                                                  int2* __restrict__ stg_s,
                                                  int* __restrict__ gcnt,
                                                  int* __restrict__ d_sr,
                                                  float* __restrict__ d_norm,
                                                  int* __restrict__ offs_d,
                                                  int* __restrict__ cnt_d) {
    __shared__ int2 sorted[CAPSTG];
    __shared__ int2 sorted2[CAPSTG];
    __shared__ int h[128], off[128], cur[128];
    __shared__ int sc[512];
    __shared__ int shist[NPART], sloff[NPART], scur[NPART], sgbase[NPART];
    __shared__ int kb;
    int p = blockIdx.x;
    int base = p * CAPSTG;
    int n = min(gcur_d[p] - base, CAPSTG);
    int t = threadIdx.x;
    if (t < 128) h[t] = 0;
    __syncthreads();
    for (int s = t; s < n; s += 256)
        atomicAdd(&h[stg_d[base + s].y & 127], 1);
    __syncthreads();
    if (t < 128) sc[t] = h[t];
    __syncthreads();
    scan128_incl(sc);
    if (t < 128) { int lo = t ? sc[t - 1] : 0; off[t] = lo; cur[t] = lo; }
    if (t == 0) kb = atomicAdd(&gcnt[0], n);
    __syncthreads();
    for (int s = t; s < n; s += 256) {
        int2 it = stg_d[base + s];
        int rk = atomicAdd(&cur[it.y & 127], 1);
        sorted[rk] = it;
    }
    __syncthreads();
    int kbase = kb;
    for (int s = t; s < n; s += 256) {
        int2 it = sorted[s];
        int key = it.y & 127;
        int r = it.x >> 16;
        int o = off[key], oe = o + h[key];
        int c = 0;
        for (int kk = o; kk < oe; ++kk)
            c += ((sorted[kk].x >> 16) == r);
        d_sr[kbase + s] = it.x;
        d_norm[kbase + s] = 1.0f / (float)c;
    }
    if (t < 128) {
        int node = (p << 7) + t;
        if (node < NNODES) { offs_d[node] = kbase + off[t]; cnt_d[node] = h[t]; }
    }
    // ---- fused src-partition scatter of (pk, k) ----
    for (int i = t; i < NPART; i += 256) shist[i] = 0;
    __syncthreads();
    for (int s = t; s < n; s += 256)
        atomicAdd(&shist[(sorted[s].x & 0xFFFF) >> 7], 1);
    __syncthreads();
    sc[t]       = (t < NPART) ? shist[t] : 0;
    sc[t + 256] = (t + 256 < NPART) ? shist[t + 256] : 0;
    __syncthreads();
    scan512_incl(sc);
    for (int pp = t; pp < NPART; pp += 256) {
        int lo = pp ? sc[pp - 1] : 0;
        sloff[pp] = lo;
        scur[pp] = lo;
        if (shist[pp]) sgbase[pp] = atomicAdd(&gcur_s[pp], shist[pp]);
    }
    __syncthreads();
    for (int s = t; s < n; s += 256) {
        int2 it = sorted[s];
        int rk = atomicAdd(&scur[(it.x & 0xFFFF) >> 7], 1);
        sorted2[rk] = make_int2(it.x, kbase + s);
    }
    __syncthreads();
    for (int s = t; s < n; s += 256) {
        int2 it = sorted2[s];
        int pp = (it.x & 0xFFFF) >> 7;
        stg_s[sgbase[pp] + (s - sloff[pp])] = it;
    }
}

// ============================================================
// src-sort pass 2: count-sort by src&127; emits sB/s_k, offs_s/cnt_s.
// ============================================================
__global__ __launch_bounds__(256) void p2s_kernel(const int* __restrict__ gcur_s,
                                                  const int2* __restrict__ stg_s,
                                                  int* __restrict__ gcnt,
                                                  int* __restrict__ sB,
                                                  int* __restrict__ s_k,
                                                  int* __restrict__ offs_s,
                                                  int* __restrict__ cnt_s) {
    __shared__ int2 sorted[CAPSTG];
    __shared__ int h[128], off[128], cur[128], sc[128];
    __shared__ int jb;
    int p = blockIdx.x;
    int base = p * CAPSTG;
    int n = min(gcur_s[p] - base, CAPSTG);
    int t = threadIdx.x;
    if (t < 128) h[t] = 0;
    __syncthreads();
    for (int s = t; s < n; s += 256)
        atomicAdd(&h[stg_s[base + s].x & 127], 1);
    __syncthreads();
    if (t < 128) sc[t] = h[t];
    __syncthreads();
    scan128_incl(sc);
    if (t < 128) { int lo = t ? sc[t - 1] : 0; off[t] = lo; cur[t] = lo; }
    if (t == 0) jb = atomicAdd(&gcnt[1], n);
    __syncthreads();
    for (int s = t; s < n; s += 256) {
        int2 it = stg_s[base + s];
        int rk = atomicAdd(&cur[it.x & 127], 1);
        sorted[rk] = it;
    }
    __syncthreads();
    int jbase = jb;
    for (int s = t; s < n; s += 256) {
        int2 it = sorted[s];
        sB[jbase + s]  = it.x;
        s_k[jbase + s] = it.y;
    }
    if (t < 128) {
        int node = (p << 7) + t;
        if (node < NNODES) { offs_s[node] = jbase + off[t]; cnt_s[node] = h[t]; }
    }
}

// ============================================================
// layer-1 messages: basis slices packed f16-over-b in LDS; comp rows
// pre-packed. Message row padded to 64B: the edge's 4 q-lanes each store
// uint4 (8B payload + 8B zero) -> one fully-covered 64B line per edge,
// no L2 RMW fetch on the scattered store.
// ============================================================
__global__ __launch_bounds__(256) void msg1_lds(const float* __restrict__ basis1,
                                                const unsigned* __restrict__ comp_pk,
                                                const int* __restrict__ offs_s,
                                                const int* __restrict__ cnt_s,
                                                const int* __restrict__ sB,
                                                const int* __restrict__ s_k,
                                                unsigned* __restrict__ m1) {
    __shared__ unsigned bspk[GS * BSTR2];     // 8.3 KB
    __shared__ unsigned cpk[NREL * CROW2];    // 7.2 KB
    int src0 = blockIdx.x * GS;
    int t = threadIdx.x;
    for (int i = t; i < (NREL * CROW2) / 4; i += 256)
        ((uint4*)cpk)[i] = ((const uint4*)comp_pk)[i];
    for (int i4 = t; i4 < 15 * 32; i4 += 256) {
        int b2 = i4 >> 5;
        int w  = i4 & 31;
        const float4* bp = (const float4*)basis1;
        float4 a = bp[(size_t)(2 * b2)     * (NNODES * 4) + (size_t)src0 * 4 + w];
        float4 b = bp[(size_t)(2 * b2 + 1) * (NNODES * 4) + (size_t)src0 * 4 + w];
        int s = w >> 2, q = w & 3;
        uint4 o;
        o.x = pk2(a.x, b.x);
        o.y = pk2(a.y, b.y);
        o.z = pk2(a.z, b.z);
        o.w = pk2(a.w, b.w);
        *((uint4*)(bspk + s * BSTR2 + b2 * 16 + q * 4)) = o;
    }
    __syncthreads();
    int n0 = offs_s[src0];
    int lastS = src0 + GS - 1;
    int n1 = offs_s[lastS] + cnt_s[lastS];
    for (int ii = n0 * 4 + t; ii < n1 * 4; ii += 256) {
        int j = ii >> 2;
        int q = ii & 3;
        int pk = sB[j];
        int k  = s_k[j];
        int src = pk & 0xFFFF;
        int r   = pk >> 16;
        const uint4* crow = (const uint4*)(cpk + r * CROW2);
        uint4 c0 = crow[0], c1 = crow[1], c2 = crow[2], c3 = crow[3];
        const unsigned* bw = bspk + (src - src0) * BSTR2 + q * 4;
        float a0 = 0.f, a1 = 0.f, a2 = 0.f, a3 = 0.f;
#define MSG1_STEP(B2, CB) { \
        uint4 v = *((const uint4*)(bw + (B2) * 16)); \
        a0 = fd2(v.x, (CB), a0); \
        a1 = fd2(v.y, (CB), a1); \
        a2 = fd2(v.z, (CB), a2); \
        a3 = fd2(v.w, (CB), a3); }
        MSG1_STEP(0,  c0.x) MSG1_STEP(1,  c0.y) MSG1_STEP(2,  c0.z) MSG1_STEP(3,  c0.w)
        MSG1_STEP(4,  c1.x) MSG1_STEP(5,  c1.y) MSG1_STEP(6,  c1.z) MSG1_STEP(7,  c1.w)
        MSG1_STEP(8,  c2.x) MSG1_STEP(9,  c2.y) MSG1_STEP(10, c2.z) MSG1_STEP(11, c2.w)
        MSG1_STEP(12, c3.x) MSG1_STEP(13, c3.y) MSG1_STEP(14, c3.z)
#undef MSG1_STEP
        // 64B-padded row: lane q writes 16B at k*64 + q*16 -> full-line coverage
        ((uint4*)m1)[(size_t)k * 4 + q] =
            make_uint4(pk2(a0, a1), pk2(a2, a3), 0u, 0u);
    }
}

// ============================================================
// layer-1 gather: thread per (dst, h-quad); m1 64B rows, dst-ordered ->
// stride-64 uint2 payload reads; fuses norm + root1 + bias1 + relu.
// Writes h (f32) and h16 (f16, for msg2).
// ============================================================
__global__ __launch_bounds__(256) void gather1_flat(const unsigned* __restrict__ m1,
                                                    const float* __restrict__ d_norm,
                                                    const int* __restrict__ offs_d,
                                                    const int* __restrict__ cnt_d,
                                                    const float* __restrict__ root1,
                                                    const float* __restrict__ bias1,
                                                    float* __restrict__ h,
                                                    unsigned* __restrict__ h16) {
    int idx = blockIdx.x * blockDim.x + threadIdx.x;
    if (idx >= NNODES * 4) return;
    int dst = idx >> 2;
    int q   = idx & 3;
    int k0 = offs_d[dst];
    int k1 = k0 + cnt_d[dst];
    float4 acc = make_float4(0.f, 0.f, 0.f, 0.f);
    for (int k = k0; k < k1; ++k) {
        uint2 v = *((const uint2*)(m1 + (size_t)k * 16 + q * 4));
        float nm = d_norm[k];
        h2 x = uph(v.x), y = uph(v.y);
        acc.x = fmaf(nm, (float)x.x, acc.x);
        acc.y = fmaf(nm, (float)x.y, acc.y);
        acc.z = fmaf(nm, (float)y.x, acc.z);
        acc.w = fmaf(nm, (float)y.y, acc.w);
    }
    float4 rt = ((const float4*)root1)[idx];
    float4 bi = ((const float4*)bias1)[q];
    float4 o;
    o.x = fmaxf(acc.x + rt.x + bi.x, 0.f);
    o.y = fmaxf(acc.y + rt.y + bi.y, 0.f);
    o.z = fmaxf(acc.z + rt.z + bi.z, 0.f);
    o.w = fmaxf(acc.w + rt.w + bi.w, 0.f);
    ((float4*)h)[idx] = o;
    ((uint2*)h16)[idx] = make_uint2(pk2(o.x, o.y), pk2(o.z, o.w));
}

// ============================================================
// W2 packed f16: w2pk[(r*8+c)*8 + p] = (W2[r][2p][c], W2[r][2p+1][c]);
// r2t[c][hh] = root2[hh][c].
// ============================================================
__global__ __launch_bounds__(256) void w2pk_kernel(const float* __restrict__ basis2,
                                                   const float* __restrict__ comp2,
                                                   const float* __restrict__ root2,
                                                   unsigned* __restrict__ w2pk,
                                                   float* __restrict__ r2t) {
    int i = blockIdx.x * blockDim.x + threadIdx.x;
    if (i >= NREL * NCLS * 8) return;
    int r = i >> 6;
    int c = (i >> 3) & (NCLS - 1);
    int p = i & 7;
    float a0 = 0.f, a1 = 0.f;
#pragma unroll
    for (int b = 0; b < NBASIS; ++b) {
        float cb = comp2[r * NBASIS + b];
        a0 = fmaf(cb, basis2[(b * HDIM + 2 * p)     * NCLS + c], a0);
        a1 = fmaf(cb, basis2[(b * HDIM + 2 * p + 1) * NCLS + c], a1);
    }
    w2pk[i] = pk2(a0, a1);
    if (i < HDIM * NCLS) {
        int c2 = i >> 4;
        int k2 = i & (HDIM - 1);
        r2t[i] = root2[k2 * NCLS + c2];
    }
}

// ============================================================
// layer-2 messages, edge-parallel: thread per (edge-slot k, class c).
// ============================================================
__global__ __launch_bounds__(256) void msg2_kernel(const unsigned* __restrict__ h16,
                                                   const unsigned* __restrict__ w2pk,
                                                   const int* __restrict__ d_sr,
                                                   const float* __restrict__ d_norm,
                                                   float* __restrict__ m2) {
    int idx = blockIdx.x * blockDim.x + threadIdx.x;   // NEDGE*8 exact
    int k = idx >> 3;
    int c = idx & (NCLS - 1);
    int pk = d_sr[k];
    float nm = d_norm[k];
    int src = pk & 0xFFFF;
    int r   = pk >> 16;
    const uint4* __restrict__ hp = (const uint4*)(h16 + src * 8);
    const uint4* __restrict__ wp = (const uint4*)(w2pk + (r * NCLS + c) * 8);
    uint4 h0 = hp[0], h1 = hp[1];
    uint4 w0 = wp[0], w1 = wp[1];
    float a = 0.f;
    a = fd2(h0.x, w0.x, a);
    a = fd2(h0.y, w0.y, a);
    a = fd2(h0.z, w0.z, a);
    a = fd2(h0.w, w0.w, a);
    a = fd2(h1.x, w1.x, a);
    a = fd2(h1.y, w1.y, a);
    a = fd2(h1.z, w1.z, a);
    a = fd2(h1.w, w1.w, a);
    m2[idx] = nm * a;
}

// ============================================================
// layer-2 gather: thread per (dst, c); sequential m2 reads;
// fused root2 + bias2 + log_softmax (8-lane shfl).
// ============================================================
__global__ __launch_bounds__(256) void gather2_kernel(const float* __restrict__ m2,
                                                      const float* __restrict__ h,
                                                      const float* __restrict__ r2t,
                                                      const int* __restrict__ offs_d,
                                                      const int* __restrict__ cnt_d,
                                                      const float* __restrict__ bias2,
                                                      float* __restrict__ out) {
    int idx = blockIdx.x * blockDim.x + threadIdx.x;
    if (idx >= NNODES * NCLS) return;
    int dst = idx >> 3;
    int c   = idx & (NCLS - 1);
    int k0 = offs_d[dst];
    int k1 = k0 + cnt_d[dst];
    float acc = 0.f;
    for (int k = k0; k < k1; ++k)
        acc += m2[k * NCLS + c];
    float v = acc + bias2[c];
    const float4* __restrict__ hd = (const float4*)h + dst * 4;
    const float4* __restrict__ rp = (const float4*)r2t + c * 4;
#pragma unroll
    for (int qq = 0; qq < 4; ++qq) {
        float4 hv = hd[qq];
        float4 rv = rp[qq];
        v = fmaf(hv.x, rv.x, v);
        v = fmaf(hv.y, rv.y, v);
        v = fmaf(hv.z, rv.z, v);
        v = fmaf(hv.w, rv.w, v);
    }
    float mx = v;
    mx = fmaxf(mx, __shfl_xor(mx, 1));
    mx = fmaxf(mx, __shfl_xor(mx, 2));
    mx = fmaxf(mx, __shfl_xor(mx, 4));
    float s = expf(v - mx);
    s += __shfl_xor(s, 1);
    s += __shfl_xor(s, 2);
    s += __shfl_xor(s, 4);
    out[idx] = v - mx - logf(s);
}

// ============================================================
// fallback (flat atomic path; needs ~23.3 MB)
// ============================================================
__global__ __launch_bounds__(256) void degcnt_fb(const int* __restrict__ ei,
                                                 const int* __restrict__ et,
                                                 int* __restrict__ deg) {
    int e = blockIdx.x * blockDim.x + threadIdx.x;
    if (e >= NEDGE) return;
    atomicAdd(&deg[ei[NEDGE + e] * NREL + et[e]], 1);
}

__global__ __launch_bounds__(256) void layer1_flat(const int* __restrict__ ei,
                                                   const int* __restrict__ et,
                                                   const float* __restrict__ basis1,
                                                   const float* __restrict__ comp1,
                                                   const int* __restrict__ deg,
                                                   float* __restrict__ h) {
    long long idx = (long long)blockIdx.x * blockDim.x + threadIdx.x;
    if (idx >= (long long)NEDGE * HDIM) return;
    int e  = (int)(idx >> 4);
    int hh = (int)(idx & (HDIM - 1));
    int src = ei[e];
    int dst = ei[NEDGE + e];
    int r   = et[e];
    float norm = 1.0f / (float)deg[dst * NREL + r];
    const float* __restrict__ cp = comp1 + r * NBASIS;
    float acc = 0.f;
#pragma unroll
    for (int b = 0; b < NBASIS; ++b)
        acc += cp[b] * basis1[(b * NNODES + src) * HDIM + hh];
    atomicAdd(&h[dst * HDIM + hh], norm * acc);
}

__global__ __launch_bounds__(256) void relu_kernel(float* __restrict__ h,
                                                   const float* __restrict__ root1,
                                                   const float* __restrict__ bias1) {
    int i = blockIdx.x * blockDim.x + threadIdx.x;
    if (i >= NNODES * HDIM) return;
    float v = h[i] + root1[i] + bias1[i & (HDIM - 1)];
    h[i] = v > 0.f ? v : 0.f;
}

__global__ __launch_bounds__(256) void w2_kernel_fb(const float* __restrict__ basis2,
                                                    const float* __restrict__ comp2,
                                                    const float* __restrict__ root2,
                                                    float* __restrict__ w2t,
                                                    float* __restrict__ r2t) {
    int i = blockIdx.x * blockDim.x + threadIdx.x;
    if (i >= NREL * HDIM * NCLS) return;
    int kk = i & (HDIM - 1);
    int c  = (i >> 4) & (NCLS - 1);
    int r  = i >> 7;
    float acc = 0.f;
#pragma unroll
    for (int b = 0; b < NBASIS; ++b)
        acc += comp2[r * NBASIS + b] * basis2[(b * HDIM + kk) * NCLS + c];
    w2t[i] = acc;
    if (i < HDIM * NCLS) {
        int c2 = i >> 4;
        int k2 = i & (HDIM - 1);
        r2t[i] = root2[k2 * NCLS + c2];
    }
}

__global__ __launch_bounds__(256) void layer2_flat(const int* __restrict__ ei,
                                                   const int* __restrict__ et,
                                                   const float* __restrict__ h,
                                                   const float* __restrict__ w2t,
                                                   const int* __restrict__ deg,
                                                   float* __restrict__ out_tmp) {
    long long idx = (long long)blockIdx.x * blockDim.x + threadIdx.x;
    if (idx >= (long long)NEDGE * NCLS) return;
    int e = (int)(idx >> 3);
    int c = (int)(idx & (NCLS - 1));
    int src = ei[e];
    int dst = ei[NEDGE + e];
    int r   = et[e];
    float norm = 1.0f / (float)deg[dst * NREL + r];
    const float4* __restrict__ hp = (const float4*)h + src * 4;
    const float4* __restrict__ wp = (const float4*)w2t + (r * NCLS + c) * 4;
    float a = 0.f;
#pragma unroll
    for (int qq = 0; qq < 4; ++qq) {
        float4 hv = hp[qq];
        float4 wv = wp[qq];
        a = fmaf(hv.x, wv.x, a);
        a = fmaf(hv.y, wv.y, a);
        a = fmaf(hv.z, wv.z, a);
        a = fmaf(hv.w, wv.w, a);
    }
    atomicAdd(&out_tmp[dst * NCLS + c], norm * a);
}

__global__ __launch_bounds__(256) void final_kernel(const float* __restrict__ out_tmp,
                                                    const float* __restrict__ h,
                                                    const float* __restrict__ root2,
                                                    const float* __restrict__ bias2,
                                                    float* __restrict__ out) {
    int n = blockIdx.x * blockDim.x + threadIdx.x;
    if (n >= NNODES) return;
    float hv[HDIM];
#pragma unroll
    for (int i = 0; i < HDIM; ++i) hv[i] = h[n * HDIM + i];
    float v[NCLS];
    float mx = -1e30f;
#pragma unroll
    for (int c = 0; c < NCLS; ++c) {
        float acc = out_tmp[n * NCLS + c] + bias2[c];
#pragma unroll
        for (int i = 0; i < HDIM; ++i) acc += hv[i] * root2[i * NCLS + c];
        v[c] = acc;
        mx = fmaxf(mx, acc);
    }
    float s = 0.f;
#pragma unroll
    for (int c = 0; c < NCLS; ++c) s += expf(v[c] - mx);
    float ls = logf(s);
#pragma unroll
    for (int c = 0; c < NCLS; ++c) out[n * NCLS + c] = v[c] - mx - ls;
}

extern "C" void kernel_launch(void* const* d_in, const int* in_sizes, int n_in,
                              void* d_out, int out_size, void* d_ws, size_t ws_size,
                              hipStream_t stream) {
    const int*   ei     = (const int*)d_in[0];
    const int*   et     = (const int*)d_in[1];
    const float* basis1 = (const float*)d_in[2];
    const float* comp1  = (const float*)d_in[3];
    const float* root1  = (const float*)d_in[4];
    const float* bias1  = (const float*)d_in[5];
    const float* basis2 = (const float*)d_in[6];
    const float* comp2  = (const float*)d_in[7];
    const float* root2  = (const float*)d_in[8];
    const float* bias2  = (const float*)d_in[9];
    float* out = (float*)d_out;

    // ---------- primary layout (4-byte words) ----------
    int*      gcur_s  = (int*)d_ws;                            // NPART
    int*      gcur_d  = gcur_s + NPART;                        // NPART
    int*      gcnt    = gcur_d + NPART;                        // 4
    unsigned* comp_pk = (unsigned*)(gcnt + 4);                 // NREL*CROW2 = 1800
    int2*  stg_d  = (int2*)(comp_pk + NREL * CROW2);           // NPART*CAPSTG int2
    int2*  stg_s  = stg_d + (size_t)NPART * CAPSTG;            // NPART*CAPSTG int2
    int*   d_sr   = (int*)(stg_s + (size_t)NPART * CAPSTG);    // E
    float* d_norm = (float*)(d_sr + NEDGE);                    // E
    int*   sB     = (int*)(d_norm + NEDGE);                    // E
    int*   s_k    = sB + NEDGE;                                // E
    int*   offs_s = s_k + NEDGE;                               // N
    int*   cnt_s  = offs_s + NNODES;                           // N
    int*   offs_d = cnt_s + NNODES;                            // N
    int*   cnt_d  = offs_d + NNODES;                           // N  (offset even)
    unsigned* m1  = (unsigned*)(cnt_d + NNODES);               // E*16 words (64B rows)
    float* m2     = (float*)m1;                                // E*8 f32 aliases (m1 dead)
    float* h      = (float*)(m1 + (size_t)NEDGE * 16);         // N*16 f32
    unsigned* h16 = (unsigned*)(h + (size_t)NNODES * HDIM);    // N*8 u32 (16 f16)
    unsigned* w2pk = h16 + (size_t)NNODES * 8;                 // R*C*8 u32
    float* r2t    = (float*)(w2pk + (size_t)NREL * NCLS * 8);  // H*C
    size_t total_words = 2 * (size_t)NPART + 4 + NREL * CROW2 +
                         4 * (size_t)NPART * CAPSTG +
                         4 * (size_t)NEDGE + 4 * (size_t)NNODES +
                         (size_t)NEDGE * 16 + (size_t)NNODES * HDIM +
                         (size_t)NNODES * 8 + (size_t)NREL * NCLS * 8 + HDIM * NCLS;

    if (ws_size >= total_words * sizeof(float)) {
        initc_kernel<<<8, 256, 0, stream>>>(gcur_s, gcur_d, gcnt, comp1, comp_pk);
        p1d_kernel<<<P1BLK, 256, 0, stream>>>(ei, et, gcur_d, stg_d);
        p2d_kernel<<<NPART - 1, 256, 0, stream>>>(gcur_d, stg_d, gcur_s, stg_s, gcnt,
                                                  d_sr, d_norm, offs_d, cnt_d);
        p2s_kernel<<<NPART - 1, 256, 0, stream>>>(gcur_s, stg_s, gcnt, sB, s_k, offs_s, cnt_s);

        msg1_lds<<<NNODES / GS, 256, 0, stream>>>(basis1, comp_pk, offs_s, cnt_s, sB, s_k, m1);
        gather1_flat<<<(NNODES * 4 + 255) / 256, 256, 0, stream>>>(
            m1, d_norm, offs_d, cnt_d, root1, bias1, h, h16);
        w2pk_kernel<<<(NREL * NCLS * 8 + 255) / 256, 256, 0, stream>>>(basis2, comp2, root2,
                                                                       w2pk, r2t);
        msg2_kernel<<<(NEDGE * NCLS) / 256, 256, 0, stream>>>(h16, w2pk, d_sr, d_norm, m2);
        gather2_kernel<<<(NNODES * NCLS + 255) / 256, 256, 0, stream>>>(
            m2, h, r2t, offs_d, cnt_d, bias2, out);
        return;
    }

    // ---------- fallback: flat atomic path (~23.3 MB) ----------
    {
        int*   deg_f   = (int*)d_ws;                               // N*R  (zero)
        float* h_f     = (float*)(deg_f + (size_t)NNODES * NREL);  // N*H  (zero)
        float* out_tmp = h_f + (size_t)NNODES * HDIM;              // N*C  (zero)
        size_t zw = (size_t)NNODES * NREL + NNODES * HDIM + NNODES * NCLS;
        float* w2t_f   = out_tmp + (size_t)NNODES * NCLS;          // R*H*C
        float* r2t_f   = w2t_f + (size_t)NREL * HDIM * NCLS;       // H*C

        (void)hipMemsetAsync(d_ws, 0, zw * sizeof(float), stream);
        degcnt_fb<<<(NEDGE + 255) / 256, 256, 0, stream>>>(ei, et, deg_f);
        layer1_flat<<<((size_t)NEDGE * HDIM + 255) / 256, 256, 0, stream>>>(
            ei, et, basis1, comp1, deg_f, h_f);
        relu_kernel<<<(NNODES * HDIM + 255) / 256, 256, 0, stream>>>(h_f, root1, bias1);
        w2_kernel_fb<<<(NREL * HDIM * NCLS + 255) / 256, 256, 0, stream>>>(basis2, comp2, root2,
                                                                           w2t_f, r2t_f);
        layer2_flat<<<((size_t)NEDGE * NCLS + 255) / 256, 256, 0, stream>>>(
            ei, et, h_f, w2t_f, deg_f, out_tmp);
        final_kernel<<<(NNODES + 255) / 256, 256, 0, stream>>>(out_tmp, h_f, root2, bias2, out);
    }
}

// Round 16
// 160.845 us; speedup vs baseline: 1.0059x; 1.0059x over previous
//
#include <hip/hip_runtime.h>

#define NNODES 50000
#define NREL   90
#define NEDGE  800000
#define HDIM   16
#define NBASIS 30
#define NCLS   8
#define NPART  392    // partitions = node>>7 ; 0..390 used
#define CH     2048   // edges per pass-1 block (391 blocks)
#define P1BLK  ((NEDGE + CH - 1) / CH)
#define CAPSTG 2816   // fixed staging stride per partition (mean 2046, sigma 45)
#define GS     8      // srcs per msg1 block (128 % GS == 0 -> block stays in one partition)
#define BSTR2  260    // per-src packed slice stride in u32 (15*16=240 + pad)
#define CROW2  20     // packed comp row stride in u32 (15 + pad; 16B aligned)

typedef __fp16 h2 __attribute__((ext_vector_type(2)));

static __device__ __forceinline__ unsigned pk2(float a, float b) {
    h2 p = __builtin_amdgcn_cvt_pkrtz(a, b);
    return __builtin_bit_cast(unsigned, p);
}
static __device__ __forceinline__ h2 uph(unsigned u) {
    return __builtin_bit_cast(h2, u);
}
static __device__ __forceinline__ float fd2(unsigned a, unsigned b, float c) {
#if __has_builtin(__builtin_amdgcn_fdot2)
    return __builtin_amdgcn_fdot2(uph(a), uph(b), c, false);
#else
    h2 x = uph(a), y = uph(b);
    return fmaf((float)x.y, (float)y.y, fmaf((float)x.x, (float)y.x, c));
#endif
}

// ---------------- parallel inclusive scans in LDS ----------------
__device__ __forceinline__ void scan512_incl(int* sc) {
    int t = threadIdx.x;
#pragma unroll
    for (int d = 1; d < 512; d <<= 1) {
        int v0 = sc[t];
        int a0 = (t >= d) ? sc[t - d] : 0;
        int v1 = sc[t + 256];
        int a1 = sc[t + 256 - d];
        __syncthreads();
        sc[t] = v0 + a0;
        sc[t + 256] = v1 + a1;
        __syncthreads();
    }
}

__device__ __forceinline__ void scan128_incl(int* sc) {
    int t = threadIdx.x;
#pragma unroll
    for (int d = 1; d < 128; d <<= 1) {
        int v = 0, a = 0;
        if (t < 128) { v = sc[t]; a = (t >= d) ? sc[t - d] : 0; }
        __syncthreads();
        if (t < 128) sc[t] = v + a;
        __syncthreads();
    }
}

// ============================================================
// init: cursors, gcnt, pre-packed f16 comp1 rows
// ============================================================
__global__ __launch_bounds__(256) void initc_kernel(int* __restrict__ gcur_s,
                                                    int* __restrict__ gcur_d,
                                                    int* __restrict__ gcnt,
                                                    const float* __restrict__ comp1,
                                                    unsigned* __restrict__ comp_pk) {
    int t = blockIdx.x * 256 + threadIdx.x;
    if (t < NPART) { gcur_s[t] = t * CAPSTG; gcur_d[t] = t * CAPSTG; }
    else if (t == NPART) { gcnt[0] = 0; gcnt[1] = 0; }
    int i = t - 512;
    if (i >= 0 && i < NREL * 15) {
        int r = i / 15;
        int b2 = i - r * 15;
        comp_pk[r * CROW2 + b2] = pk2(comp1[r * NBASIS + 2 * b2],
                                      comp1[r * NBASIS + 2 * b2 + 1]);
    }
    if (i >= NREL * 15 && i < NREL * 15 + NREL * (CROW2 - 15)) {
        int j = i - NREL * 15;
        int r = j / (CROW2 - 15);
        int pcol = 15 + (j - r * (CROW2 - 15));
        comp_pk[r * CROW2 + pcol] = 0;
    }
}

// ============================================================
// src-sort pass 1: partition raw edges by src>>7 into fixed-stride staging.
// record: x = dst | r<<16 , y = src
// ============================================================
__global__ __launch_bounds__(256) void p1s_kernel(const int* __restrict__ ei,
                                                  const int* __restrict__ et,
                                                  int* __restrict__ gcur_s,
                                                  int2* __restrict__ stg_s) {
    __shared__ int2 sorted[CH];
    __shared__ int hist[NPART], loff[NPART], cur[NPART], gbase[NPART];
    __shared__ int sc[512];
    int base = blockIdx.x * CH;
    int nitems = min(CH, NEDGE - base);
    int t = threadIdx.x;
    for (int i = t; i < NPART; i += 256) hist[i] = 0;
    __syncthreads();
    for (int i = t; i < nitems; i += 256)
        atomicAdd(&hist[ei[base + i] >> 7], 1);
    __syncthreads();
    sc[t]       = (t < NPART) ? hist[t] : 0;
    sc[t + 256] = (t + 256 < NPART) ? hist[t + 256] : 0;
    __syncthreads();
    scan512_incl(sc);
    for (int p = t; p < NPART; p += 256) {
        int lo = p ? sc[p - 1] : 0;
        loff[p] = lo;
        cur[p] = lo;
        if (hist[p]) gbase[p] = atomicAdd(&gcur_s[p], hist[p]);
    }
    __syncthreads();
    for (int i = t; i < nitems; i += 256) {
        int e = base + i;
        int src = ei[e], dst = ei[NEDGE + e], r = et[e];
        int rk = atomicAdd(&cur[src >> 7], 1);
        sorted[rk] = make_int2(dst | (r << 16), src);
    }
    __syncthreads();
    for (int s = t; s < nitems; s += 256) {
        int2 it = sorted[s];
        int p = it.y >> 7;
        stg_s[gbase[p] + (s - loff[p])] = it;
    }
}

// ============================================================
// src-sort pass 2 (+ fused dst-partition scatter):
//  - count-sort staged items by src&127 -> j-order (compact via gcnt[1])
//  - emit sB[j] = src | r<<16, offs_s/cnt_s (coalesced)
//  - group by dst>>7 in LDS (partition id packed into y bits 20..28),
//    reserve dst staging, coalesced write of (src|r<<16|(dst&127)<<23, j)
// ============================================================
__global__ __launch_bounds__(256) void p2s_kernel(const int* __restrict__ gcur_s,
                                                  const int2* __restrict__ stg_s,
                                                  int* __restrict__ gcur_d,
                                                  int2* __restrict__ stg_d,
                                                  int* __restrict__ gcnt,
                                                  int* __restrict__ sB,
                                                  int* __restrict__ offs_s,
                                                  int* __restrict__ cnt_s) {
    __shared__ int2 sorted[CAPSTG];
    __shared__ int2 sorted2[CAPSTG];
    __shared__ int h[128], off[128], cur[128];
    __shared__ int sc[512];
    __shared__ int shist[NPART], sloff[NPART], scur[NPART], sgbase[NPART];
    __shared__ int jb;
    int p = blockIdx.x;
    int base = p * CAPSTG;
    int n = min(gcur_s[p] - base, CAPSTG);
    int t = threadIdx.x;
    if (t < 128) h[t] = 0;
    __syncthreads();
    for (int s = t; s < n; s += 256)
        atomicAdd(&h[stg_s[base + s].y & 127], 1);
    __syncthreads();
    if (t < 128) sc[t] = h[t];
    __syncthreads();
    scan128_incl(sc);
    if (t < 128) { int lo = t ? sc[t - 1] : 0; off[t] = lo; cur[t] = lo; }
    if (t == 0) jb = atomicAdd(&gcnt[1], n);
    __syncthreads();
    for (int s = t; s < n; s += 256) {
        int2 it = stg_s[base + s];
        int rk = atomicAdd(&cur[it.y & 127], 1);
        sorted[rk] = it;
    }
    __syncthreads();
    int jbase = jb;
    for (int s = t; s < n; s += 256) {
        int2 it = sorted[s];
        int r = it.x >> 16;
        sB[jbase + s] = it.y | (r << 16);           // src | r<<16
    }
    if (t < 128) {
        int node = (p << 7) + t;
        if (node < NNODES) { offs_s[node] = jbase + off[t]; cnt_s[node] = h[t]; }
    }
    // ---- fused dst-partition scatter ----
    for (int i = t; i < NPART; i += 256) shist[i] = 0;
    __syncthreads();
    for (int s = t; s < n; s += 256)
        atomicAdd(&shist[(sorted[s].x & 0xFFFF) >> 7], 1);
    __syncthreads();
    sc[t]       = (t < NPART) ? shist[t] : 0;
    sc[t + 256] = (t + 256 < NPART) ? shist[t + 256] : 0;
    __syncthreads();
    scan512_incl(sc);
    for (int pp = t; pp < NPART; pp += 256) {
        int lo = pp ? sc[pp - 1] : 0;
        sloff[pp] = lo;
        scur[pp] = lo;
        if (shist[pp]) sgbase[pp] = atomicAdd(&gcur_d[pp], shist[pp]);
    }
    __syncthreads();
    for (int s = t; s < n; s += 256) {
        int2 it = sorted[s];
        int dst = it.x & 0xFFFF;
        int r   = it.x >> 16;
        int src = it.y;
        int pp  = dst >> 7;
        int rk = atomicAdd(&scur[pp], 1);
        sorted2[rk] = make_int2(src | (r << 16) | ((dst & 127) << 23),
                                (jbase + s) | (pp << 20));
    }
    __syncthreads();
    for (int s = t; s < n; s += 256) {
        int2 it = sorted2[s];
        int pp = ((unsigned)it.y) >> 20;
        stg_d[sgbase[pp] + (s - sloff[pp])] = make_int2(it.x, it.y & 0xFFFFF);
    }
}

// ============================================================
// dst-sort pass 2: count-sort by (x>>23)&127 -> k-order; per-edge norm
// from in-LDS (dst,r) segments. emits d_sr[k]=src|r<<16, d_j[k],
// d_norm, offs_d/cnt_d. All writes coalesced.
// ============================================================
__global__ __launch_bounds__(256) void p2d_kernel(const int* __restrict__ gcur_d,
                                                  const int2* __restrict__ stg_d,
                                                  int* __restrict__ gcnt,
                                                  int* __restrict__ d_sr,
                                                  int* __restrict__ d_j,
                                                  float* __restrict__ d_norm,
                                                  int* __restrict__ offs_d,
                                                  int* __restrict__ cnt_d) {
    __shared__ int2 sorted[CAPSTG];
    __shared__ int h[128], off[128], cur[128], sc[128];
    __shared__ int kb;
    int p = blockIdx.x;
    int base = p * CAPSTG;
    int n = min(gcur_d[p] - base, CAPSTG);
    int t = threadIdx.x;
    if (t < 128) h[t] = 0;
    __syncthreads();
    for (int s = t; s < n; s += 256)
        atomicAdd(&h[(stg_d[base + s].x >> 23) & 127], 1);
    __syncthreads();
    if (t < 128) sc[t] = h[t];
    __syncthreads();
    scan128_incl(sc);
    if (t < 128) { int lo = t ? sc[t - 1] : 0; off[t] = lo; cur[t] = lo; }
    if (t == 0) kb = atomicAdd(&gcnt[0], n);
    __syncthreads();
    for (int s = t; s < n; s += 256) {
        int2 it = stg_d[base + s];
        int rk = atomicAdd(&cur[(it.x >> 23) & 127], 1);
        sorted[rk] = it;
    }
    __syncthreads();
    int kbase = kb;
    for (int s = t; s < n; s += 256) {
        int2 it = sorted[s];
        int key = (it.x >> 23) & 127;
        int r = (it.x >> 16) & 127;
        int o = off[key], oe = o + h[key];
        int c = 0;
        for (int kk = o; kk < oe; ++kk)
            c += (((sorted[kk].x >> 16) & 127) == r);
        d_sr[kbase + s]   = it.x & 0x7FFFFF;
        d_j[kbase + s]    = it.y;
        d_norm[kbase + s] = 1.0f / (float)c;
    }
    if (t < 128) {
        int node = (p << 7) + t;
        if (node < NNODES) { offs_d[node] = kbase + off[t]; cnt_d[node] = h[t]; }
    }
}

// ============================================================
// layer-1 messages: basis slices packed f16-over-b in LDS; comp rows
// pre-packed. SEQUENTIAL f16 write at j (coalesced 25.6 MB stream).
// ============================================================
__global__ __launch_bounds__(256) void msg1_lds(const float* __restrict__ basis1,
                                                const unsigned* __restrict__ comp_pk,
                                                const int* __restrict__ offs_s,
                                                const int* __restrict__ cnt_s,
                                                const int* __restrict__ sB,
                                                unsigned* __restrict__ m1) {
    __shared__ unsigned bspk[GS * BSTR2];     // 8.3 KB
    __shared__ unsigned cpk[NREL * CROW2];    // 7.2 KB
    int src0 = blockIdx.x * GS;
    int t = threadIdx.x;
    for (int i = t; i < (NREL * CROW2) / 4; i += 256)
        ((uint4*)cpk)[i] = ((const uint4*)comp_pk)[i];
    for (int i4 = t; i4 < 15 * 32; i4 += 256) {
        int b2 = i4 >> 5;
        int w  = i4 & 31;
        const float4* bp = (const float4*)basis1;
        float4 a = bp[(size_t)(2 * b2)     * (NNODES * 4) + (size_t)src0 * 4 + w];
        float4 b = bp[(size_t)(2 * b2 + 1) * (NNODES * 4) + (size_t)src0 * 4 + w];
        int s = w >> 2, q = w & 3;
        uint4 o;
        o.x = pk2(a.x, b.x);
        o.y = pk2(a.y, b.y);
        o.z = pk2(a.z, b.z);
        o.w = pk2(a.w, b.w);
        *((uint4*)(bspk + s * BSTR2 + b2 * 16 + q * 4)) = o;
    }
    __syncthreads();
    int n0 = offs_s[src0];
    int lastS = src0 + GS - 1;
    int n1 = offs_s[lastS] + cnt_s[lastS];
    for (int ii = n0 * 4 + t; ii < n1 * 4; ii += 256) {
        int j = ii >> 2;
        int q = ii & 3;
        int pk = sB[j];
        int src = pk & 0xFFFF;
        int r   = pk >> 16;
        const uint4* crow = (const uint4*)(cpk + r * CROW2);
        uint4 c0 = crow[0], c1 = crow[1], c2 = crow[2], c3 = crow[3];
        const unsigned* bw = bspk + (src - src0) * BSTR2 + q * 4;
        float a0 = 0.f, a1 = 0.f, a2 = 0.f, a3 = 0.f;
#define MSG1_STEP(B2, CB) { \
        uint4 v = *((const uint4*)(bw + (B2) * 16)); \
        a0 = fd2(v.x, (CB), a0); \
        a1 = fd2(v.y, (CB), a1); \
        a2 = fd2(v.z, (CB), a2); \
        a3 = fd2(v.w, (CB), a3); }
        MSG1_STEP(0,  c0.x) MSG1_STEP(1,  c0.y) MSG1_STEP(2,  c0.z) MSG1_STEP(3,  c0.w)
        MSG1_STEP(4,  c1.x) MSG1_STEP(5,  c1.y) MSG1_STEP(6,  c1.z) MSG1_STEP(7,  c1.w)
        MSG1_STEP(8,  c2.x) MSG1_STEP(9,  c2.y) MSG1_STEP(10, c2.z) MSG1_STEP(11, c2.w)
        MSG1_STEP(12, c3.x) MSG1_STEP(13, c3.y) MSG1_STEP(14, c3.z)
#undef MSG1_STEP
        ((uint2*)m1)[(size_t)j * 4 + q] = make_uint2(pk2(a0, a1), pk2(a2, a3));
    }
}

// ============================================================
// layer-1 gather: thread per (dst, h-quad); m1 j-ordered (25.6 MB,
// LLC-resident) gathered via d_j[k]; 4 q-lanes of an edge read one
// coalesced 32B row. Fuses norm + root1 + bias1 + relu. Writes h + h16.
// ============================================================
__global__ __launch_bounds__(256) void gather1_flat(const unsigned* __restrict__ m1,
                                                    const int* __restrict__ d_j,
                                                    const float* __restrict__ d_norm,
                                                    const int* __restrict__ offs_d,
                                                    const int* __restrict__ cnt_d,
                                                    const float* __restrict__ root1,
                                                    const float* __restrict__ bias1,
                                                    float* __restrict__ h,
                                                    unsigned* __restrict__ h16) {
    int idx = blockIdx.x * blockDim.x + threadIdx.x;
    if (idx >= NNODES * 4) return;
    int dst = idx >> 2;
    int q   = idx & 3;
    int k0 = offs_d[dst];
    int k1 = k0 + cnt_d[dst];
    float4 acc = make_float4(0.f, 0.f, 0.f, 0.f);
    for (int k = k0; k < k1; ++k) {
        int j = d_j[k];
        uint2 v = ((const uint2*)m1)[(size_t)j * 4 + q];
        float nm = d_norm[k];
        h2 x = uph(v.x), y = uph(v.y);
        acc.x = fmaf(nm, (float)x.x, acc.x);
        acc.y = fmaf(nm, (float)x.y, acc.y);
        acc.z = fmaf(nm, (float)y.x, acc.z);
        acc.w = fmaf(nm, (float)y.y, acc.w);
    }
    float4 rt = ((const float4*)root1)[idx];
    float4 bi = ((const float4*)bias1)[q];
    float4 o;
    o.x = fmaxf(acc.x + rt.x + bi.x, 0.f);
    o.y = fmaxf(acc.y + rt.y + bi.y, 0.f);
    o.z = fmaxf(acc.z + rt.z + bi.z, 0.f);
    o.w = fmaxf(acc.w + rt.w + bi.w, 0.f);
    ((float4*)h)[idx] = o;
    ((uint2*)h16)[idx] = make_uint2(pk2(o.x, o.y), pk2(o.z, o.w));
}

// ============================================================
// W2 packed f16: w2pk[(r*8+c)*8 + p] = (W2[r][2p][c], W2[r][2p+1][c]);
// r2t[c][hh] = root2[hh][c].
// ============================================================
__global__ __launch_bounds__(256) void w2pk_kernel(const float* __restrict__ basis2,
                                                   const float* __restrict__ comp2,
                                                   const float* __restrict__ root2,
                                                   unsigned* __restrict__ w2pk,
                                                   float* __restrict__ r2t) {
    int i = blockIdx.x * blockDim.x + threadIdx.x;
    if (i >= NREL * NCLS * 8) return;
    int r = i >> 6;
    int c = (i >> 3) & (NCLS - 1);
    int p = i & 7;
    float a0 = 0.f, a1 = 0.f;
#pragma unroll
    for (int b = 0; b < NBASIS; ++b) {
        float cb = comp2[r * NBASIS + b];
        a0 = fmaf(cb, basis2[(b * HDIM + 2 * p)     * NCLS + c], a0);
        a1 = fmaf(cb, basis2[(b * HDIM + 2 * p + 1) * NCLS + c], a1);
    }
    w2pk[i] = pk2(a0, a1);
    if (i < HDIM * NCLS) {
        int c2 = i >> 4;
        int k2 = i & (HDIM - 1);
        r2t[i] = root2[k2 * NCLS + c2];
    }
}

// ============================================================
// layer-2 messages, edge-parallel: thread per (edge-slot k, class c).
// ============================================================
__global__ __launch_bounds__(256) void msg2_kernel(const unsigned* __restrict__ h16,
                                                   const unsigned* __restrict__ w2pk,
                                                   const int* __restrict__ d_sr,
                                                   const float* __restrict__ d_norm,
                                                   float* __restrict__ m2) {
    int idx = blockIdx.x * blockDim.x + threadIdx.x;   // NEDGE*8 exact
    int k = idx >> 3;
    int c = idx & (NCLS - 1);
    int pk = d_sr[k];
    float nm = d_norm[k];
    int src = pk & 0xFFFF;
    int r   = pk >> 16;
    const uint4* __restrict__ hp = (const uint4*)(h16 + src * 8);
    const uint4* __restrict__ wp = (const uint4*)(w2pk + (r * NCLS + c) * 8);
    uint4 h0 = hp[0], h1 = hp[1];
    uint4 w0 = wp[0], w1 = wp[1];
    float a = 0.f;
    a = fd2(h0.x, w0.x, a);
    a = fd2(h0.y, w0.y, a);
    a = fd2(h0.z, w0.z, a);
    a = fd2(h0.w, w0.w, a);
    a = fd2(h1.x, w1.x, a);
    a = fd2(h1.y, w1.y, a);
    a = fd2(h1.z, w1.z, a);
    a = fd2(h1.w, w1.w, a);
    m2[idx] = nm * a;
}

// ============================================================
// layer-2 gather: thread per (dst, c); sequential m2 reads;
// fused root2 + bias2 + log_softmax (8-lane shfl).
// ============================================================
__global__ __launch_bounds__(256) void gather2_kernel(const float* __restrict__ m2,
                                                      const float* __restrict__ h,
                                                      const float* __restrict__ r2t,
                                                      const int* __restrict__ offs_d,
                                                      const int* __restrict__ cnt_d,
                                                      const float* __restrict__ bias2,
                                                      float* __restrict__ out) {
    int idx = blockIdx.x * blockDim.x + threadIdx.x;
    if (idx >= NNODES * NCLS) return;
    int dst = idx >> 3;
    int c   = idx & (NCLS - 1);
    int k0 = offs_d[dst];
    int k1 = k0 + cnt_d[dst];
    float acc = 0.f;
    for (int k = k0; k < k1; ++k)
        acc += m2[k * NCLS + c];
    float v = acc + bias2[c];
    const float4* __restrict__ hd = (const float4*)h + dst * 4;
    const float4* __restrict__ rp = (const float4*)r2t + c * 4;
#pragma unroll
    for (int qq = 0; qq < 4; ++qq) {
        float4 hv = hd[qq];
        float4 rv = rp[qq];
        v = fmaf(hv.x, rv.x, v);
        v = fmaf(hv.y, rv.y, v);
        v = fmaf(hv.z, rv.z, v);
        v = fmaf(hv.w, rv.w, v);
    }
    float mx = v;
    mx = fmaxf(mx, __shfl_xor(mx, 1));
    mx = fmaxf(mx, __shfl_xor(mx, 2));
    mx = fmaxf(mx, __shfl_xor(mx, 4));
    float s = expf(v - mx);
    s += __shfl_xor(s, 1);
    s += __shfl_xor(s, 2);
    s += __shfl_xor(s, 4);
    out[idx] = v - mx - logf(s);
}

// ============================================================
// fallback (flat atomic path; needs ~23.3 MB)
// ============================================================
__global__ __launch_bounds__(256) void degcnt_fb(const int* __restrict__ ei,
                                                 const int* __restrict__ et,
                                                 int* __restrict__ deg) {
    int e = blockIdx.x * blockDim.x + threadIdx.x;
    if (e >= NEDGE) return;
    atomicAdd(&deg[ei[NEDGE + e] * NREL + et[e]], 1);
}

__global__ __launch_bounds__(256) void layer1_flat(const int* __restrict__ ei,
                                                   const int* __restrict__ et,
                                                   const float* __restrict__ basis1,
                                                   const float* __restrict__ comp1,
                                                   const int* __restrict__ deg,
                                                   float* __restrict__ h) {
    long long idx = (long long)blockIdx.x * blockDim.x + threadIdx.x;
    if (idx >= (long long)NEDGE * HDIM) return;
    int e  = (int)(idx >> 4);
    int hh = (int)(idx & (HDIM - 1));
    int src = ei[e];
    int dst = ei[NEDGE + e];
    int r   = et[e];
    float norm = 1.0f / (float)deg[dst * NREL + r];
    const float* __restrict__ cp = comp1 + r * NBASIS;
    float acc = 0.f;
#pragma unroll
    for (int b = 0; b < NBASIS; ++b)
        acc += cp[b] * basis1[(b * NNODES + src) * HDIM + hh];
    atomicAdd(&h[dst * HDIM + hh], norm * acc);
}

__global__ __launch_bounds__(256) void relu_kernel(float* __restrict__ h,
                                                   const float* __restrict__ root1,
                                                   const float* __restrict__ bias1) {
    int i = blockIdx.x * blockDim.x + threadIdx.x;
    if (i >= NNODES * HDIM) return;
    float v = h[i] + root1[i] + bias1[i & (HDIM - 1)];
    h[i] = v > 0.f ? v : 0.f;
}

__global__ __launch_bounds__(256) void w2_kernel_fb(const float* __restrict__ basis2,
                                                    const float* __restrict__ comp2,
                                                    const float* __restrict__ root2,
                                                    float* __restrict__ w2t,
                                                    float* __restrict__ r2t) {
    int i = blockIdx.x * blockDim.x + threadIdx.x;
    if (i >= NREL * HDIM * NCLS) return;
    int kk = i & (HDIM - 1);
    int c  = (i >> 4) & (NCLS - 1);
    int r  = i >> 7;
    float acc = 0.f;
#pragma unroll
    for (int b = 0; b < NBASIS; ++b)
        acc += comp2[r * NBASIS + b] * basis2[(b * HDIM + kk) * NCLS + c];
    w2t[i] = acc;
    if (i < HDIM * NCLS) {
        int c2 = i >> 4;
        int k2 = i & (HDIM - 1);
        r2t[i] = root2[k2 * NCLS + c2];
    }
}

__global__ __launch_bounds__(256) void layer2_flat(const int* __restrict__ ei,
                                                   const int* __restrict__ et,
                                                   const float* __restrict__ h,
                                                   const float* __restrict__ w2t,
                                                   const int* __restrict__ deg,
                                                   float* __restrict__ out_tmp) {
    long long idx = (long long)blockIdx.x * blockDim.x + threadIdx.x;
    if (idx >= (long long)NEDGE * NCLS) return;
    int e = (int)(idx >> 3);
    int c = (int)(idx & (NCLS - 1));
    int src = ei[e];
    int dst = ei[NEDGE + e];
    int r   = et[e];
    float norm = 1.0f / (float)deg[dst * NREL + r];
    const float4* __restrict__ hp = (const float4*)h + src * 4;
    const float4* __restrict__ wp = (const float4*)w2t + (r * NCLS + c) * 4;
    float a = 0.f;
#pragma unroll
    for (int qq = 0; qq < 4; ++qq) {
        float4 hv = hp[qq];
        float4 wv = wp[qq];
        a = fmaf(hv.x, wv.x, a);
        a = fmaf(hv.y, wv.y, a);
        a = fmaf(hv.z, wv.z, a);
        a = fmaf(hv.w, wv.w, a);
    }
    atomicAdd(&out_tmp[dst * NCLS + c], norm * a);
}

__global__ __launch_bounds__(256) void final_kernel(const float* __restrict__ out_tmp,
                                                    const float* __restrict__ h,
                                                    const float* __restrict__ root2,
                                                    const float* __restrict__ bias2,
                                                    float* __restrict__ out) {
    int n = blockIdx.x * blockDim.x + threadIdx.x;
    if (n >= NNODES) return;
    float hv[HDIM];
#pragma unroll
    for (int i = 0; i < HDIM; ++i) hv[i] = h[n * HDIM + i];
    float v[NCLS];
    float mx = -1e30f;
#pragma unroll
    for (int c = 0; c < NCLS; ++c) {
        float acc = out_tmp[n * NCLS + c] + bias2[c];
#pragma unroll
        for (int i = 0; i < HDIM; ++i) acc += hv[i] * root2[i * NCLS + c];
        v[c] = acc;
        mx = fmaxf(mx, acc);
    }
    float s = 0.f;
#pragma unroll
    for (int c = 0; c < NCLS; ++c) s += expf(v[c] - mx);
    float ls = logf(s);
#pragma unroll
    for (int c = 0; c < NCLS; ++c) out[n * NCLS + c] = v[c] - mx - ls;
}

extern "C" void kernel_launch(void* const* d_in, const int* in_sizes, int n_in,
                              void* d_out, int out_size, void* d_ws, size_t ws_size,
                              hipStream_t stream) {
    const int*   ei     = (const int*)d_in[0];
    const int*   et     = (const int*)d_in[1];
    const float* basis1 = (const float*)d_in[2];
    const float* comp1  = (const float*)d_in[3];
    const float* root1  = (const float*)d_in[4];
    const float* bias1  = (const float*)d_in[5];
    const float* basis2 = (const float*)d_in[6];
    const float* comp2  = (const float*)d_in[7];
    const float* root2  = (const float*)d_in[8];
    const float* bias2  = (const float*)d_in[9];
    float* out = (float*)d_out;

    // ---------- primary layout (4-byte words; vectors at aligned offsets) ----------
    int*      gcur_s  = (int*)d_ws;                            // NPART
    int*      gcur_d  = gcur_s + NPART;                        // NPART
    int*      gcnt    = gcur_d + NPART;                        // 4
    unsigned* comp_pk = (unsigned*)(gcnt + 4);                 // NREL*CROW2 = 1800 -> 2588 (16B-aligned)
    int2*  stg_s  = (int2*)(comp_pk + NREL * CROW2);           // NPART*CAPSTG int2
    int2*  stg_d  = stg_s + (size_t)NPART * CAPSTG;            // NPART*CAPSTG int2
    int*   d_sr   = (int*)(stg_d + (size_t)NPART * CAPSTG);    // E
    float* d_norm = (float*)(d_sr + NEDGE);                    // E
    int*   sB     = (int*)(d_norm + NEDGE);                    // E
    int*   d_j    = sB + NEDGE;                                // E
    int*   offs_s = d_j + NEDGE;                               // N
    int*   cnt_s  = offs_s + NNODES;                           // N
    int*   offs_d = cnt_s + NNODES;                            // N
    int*   cnt_d  = offs_d + NNODES;                           // N
    unsigned* m1  = (unsigned*)(cnt_d + NNODES);               // E*8 words (E*16 f16, 32B rows)
    float* m2     = (float*)m1;                                // E*8 f32 aliases (m1 dead after gather1)
    float* h      = (float*)(m1 + (size_t)NEDGE * 8);          // N*16 f32
    unsigned* h16 = (unsigned*)(h + (size_t)NNODES * HDIM);    // N*8 u32 (16 f16)
    unsigned* w2pk = h16 + (size_t)NNODES * 8;                 // R*C*8 u32
    float* r2t    = (float*)(w2pk + (size_t)NREL * NCLS * 8);  // H*C
    size_t total_words = 2 * (size_t)NPART + 4 + NREL * CROW2 +
                         4 * (size_t)NPART * CAPSTG +
                         4 * (size_t)NEDGE + 4 * (size_t)NNODES +
                         (size_t)NEDGE * 8 + (size_t)NNODES * HDIM +
                         (size_t)NNODES * 8 + (size_t)NREL * NCLS * 8 + HDIM * NCLS;

    if (ws_size >= total_words * sizeof(float)) {
        initc_kernel<<<8, 256, 0, stream>>>(gcur_s, gcur_d, gcnt, comp1, comp_pk);
        p1s_kernel<<<P1BLK, 256, 0, stream>>>(ei, et, gcur_s, stg_s);
        p2s_kernel<<<NPART - 1, 256, 0, stream>>>(gcur_s, stg_s, gcur_d, stg_d, gcnt,
                                                  sB, offs_s, cnt_s);
        p2d_kernel<<<NPART - 1, 256, 0, stream>>>(gcur_d, stg_d, gcnt,
                                                  d_sr, d_j, d_norm, offs_d, cnt_d);

        msg1_lds<<<NNODES / GS, 256, 0, stream>>>(basis1, comp_pk, offs_s, cnt_s, sB, m1);
        gather1_flat<<<(NNODES * 4 + 255) / 256, 256, 0, stream>>>(
            m1, d_j, d_norm, offs_d, cnt_d, root1, bias1, h, h16);
        w2pk_kernel<<<(NREL * NCLS * 8 + 255) / 256, 256, 0, stream>>>(basis2, comp2, root2,
                                                                       w2pk, r2t);
        msg2_kernel<<<(NEDGE * NCLS) / 256, 256, 0, stream>>>(h16, w2pk, d_sr, d_norm, m2);
        gather2_kernel<<<(NNODES * NCLS + 255) / 256, 256, 0, stream>>>(
            m2, h, r2t, offs_d, cnt_d, bias2, out);
        return;
    }

    // ---------- fallback: flat atomic path (~23.3 MB) ----------
    {
        int*   deg_f   = (int*)d_ws;                               // N*R  (zero)
        float* h_f     = (float*)(deg_f + (size_t)NNODES * NREL);  // N*H  (zero)
        float* out_tmp = h_f + (size_t)NNODES * HDIM;              // N*C  (zero)
        size_t zw = (size_t)NNODES * NREL + NNODES * HDIM + NNODES * NCLS;
        float* w2t_f   = out_tmp + (size_t)NNODES * NCLS;          // R*H*C
        float* r2t_f   = w2t_f + (size_t)NREL * HDIM * NCLS;       // H*C

        (void)hipMemsetAsync(d_ws, 0, zw * sizeof(float), stream);
        degcnt_fb<<<(NEDGE + 255) / 256, 256, 0, stream>>>(ei, et, deg_f);
        layer1_flat<<<((size_t)NEDGE * HDIM + 255) / 256, 256, 0, stream>>>(
            ei, et, basis1, comp1, deg_f, h_f);
        relu_kernel<<<(NNODES * HDIM + 255) / 256, 256, 0, stream>>>(h_f, root1, bias1);
        w2_kernel_fb<<<(NREL * HDIM * NCLS + 255) / 256, 256, 0, stream>>>(basis2, comp2, root2,
                                                                           w2t_f, r2t_f);
        layer2_flat<<<((size_t)NEDGE * NCLS + 255) / 256, 256, 0, stream>>>(
            ei, et, h_f, w2t_f, deg_f, out_tmp);
        final_kernel<<<(NNODES + 255) / 256, 256, 0, stream>>>(out_tmp, h_f, root2, bias2, out);
    }
}

// Round 17
// 152.952 us; speedup vs baseline: 1.0578x; 1.0516x over previous
//
#include <hip/hip_runtime.h>

#define NNODES 50000
#define NREL   90
#define NEDGE  800000
#define HDIM   16
#define NBASIS 30
#define NCLS   8
#define NPART  392    // partitions = node>>7 ; 0..390 used
#define CH     2048   // edges per pass-1 block (391 blocks)
#define P1BLK  ((NEDGE + CH - 1) / CH)
#define CAPSTG 2816   // fixed staging stride per partition (mean 2046, sigma 45)
#define GS     8      // srcs per msg1 block
#define BSTR2  260    // per-src packed slice stride in u32 (15*16=240 + pad)
#define CROW2  20     // packed comp row stride in u32 (15 + pad; 16B aligned)

typedef __fp16 h2 __attribute__((ext_vector_type(2)));

static __device__ __forceinline__ unsigned pk2(float a, float b) {
    h2 p = __builtin_amdgcn_cvt_pkrtz(a, b);
    return __builtin_bit_cast(unsigned, p);
}
static __device__ __forceinline__ h2 uph(unsigned u) {
    return __builtin_bit_cast(h2, u);
}
static __device__ __forceinline__ float fd2(unsigned a, unsigned b, float c) {
#if __has_builtin(__builtin_amdgcn_fdot2)
    return __builtin_amdgcn_fdot2(uph(a), uph(b), c, false);
#else
    h2 x = uph(a), y = uph(b);
    return fmaf((float)x.y, (float)y.y, fmaf((float)x.x, (float)y.x, c));
#endif
}

// ---------------- parallel inclusive scans in LDS ----------------
__device__ __forceinline__ void scan512_incl(int* sc) {
    int t = threadIdx.x;
#pragma unroll
    for (int d = 1; d < 512; d <<= 1) {
        int v0 = sc[t];
        int a0 = (t >= d) ? sc[t - d] : 0;
        int v1 = sc[t + 256];
        int a1 = sc[t + 256 - d];
        __syncthreads();
        sc[t] = v0 + a0;
        sc[t + 256] = v1 + a1;
        __syncthreads();
    }
}

__device__ __forceinline__ void scan128_incl(int* sc) {
    int t = threadIdx.x;
#pragma unroll
    for (int d = 1; d < 128; d <<= 1) {
        int v = 0, a = 0;
        if (t < 128) { v = sc[t]; a = (t >= d) ? sc[t - d] : 0; }
        __syncthreads();
        if (t < 128) sc[t] = v + a;
        __syncthreads();
    }
}

// ============================================================
// init: cursors, gcnt, pre-packed f16 comp1 rows
// ============================================================
__global__ __launch_bounds__(256) void initc_kernel(int* __restrict__ gcur_s,
                                                    int* __restrict__ gcur_d,
                                                    int* __restrict__ gcnt,
                                                    const float* __restrict__ comp1,
                                                    unsigned* __restrict__ comp_pk) {
    int t = blockIdx.x * 256 + threadIdx.x;
    if (t < NPART) { gcur_s[t] = t * CAPSTG; gcur_d[t] = t * CAPSTG; }
    else if (t == NPART) { gcnt[0] = 0; gcnt[1] = 0; }
    int i = t - 512;
    if (i >= 0 && i < NREL * 15) {
        int r = i / 15;
        int b2 = i - r * 15;
        comp_pk[r * CROW2 + b2] = pk2(comp1[r * NBASIS + 2 * b2],
                                      comp1[r * NBASIS + 2 * b2 + 1]);
    }
    if (i >= NREL * 15 && i < NREL * 15 + NREL * (CROW2 - 15)) {
        int j = i - NREL * 15;
        int r = j / (CROW2 - 15);
        int pcol = 15 + (j - r * (CROW2 - 15));
        comp_pk[r * CROW2 + pcol] = 0;
    }
}

// ============================================================
// dst-sort pass 1: partition raw edges by dst>>7 into fixed-stride staging.
// ============================================================
__global__ __launch_bounds__(256) void p1d_kernel(const int* __restrict__ ei,
                                                  const int* __restrict__ et,
                                                  int* __restrict__ gcur_d,
                                                  int2* __restrict__ stg_d) {
    __shared__ int2 sorted[CH];
    __shared__ int hist[NPART], loff[NPART], cur[NPART], gbase[NPART];
    __shared__ int sc[512];
    int base = blockIdx.x * CH;
    int nitems = min(CH, NEDGE - base);
    int t = threadIdx.x;
    for (int i = t; i < NPART; i += 256) hist[i] = 0;
    __syncthreads();
    for (int i = t; i < nitems; i += 256)
        atomicAdd(&hist[ei[NEDGE + base + i] >> 7], 1);
    __syncthreads();
    sc[t]       = (t < NPART) ? hist[t] : 0;
    sc[t + 256] = (t + 256 < NPART) ? hist[t + 256] : 0;
    __syncthreads();
    scan512_incl(sc);
    for (int p = t; p < NPART; p += 256) {
        int lo = p ? sc[p - 1] : 0;
        loff[p] = lo;
        cur[p] = lo;
        if (hist[p]) gbase[p] = atomicAdd(&gcur_d[p], hist[p]);
    }
    __syncthreads();
    for (int i = t; i < nitems; i += 256) {
        int e = base + i;
        int src = ei[e], dst = ei[NEDGE + e], r = et[e];
        int rk = atomicAdd(&cur[dst >> 7], 1);
        sorted[rk] = make_int2(src | (r << 16), dst);
    }
    __syncthreads();
    for (int s = t; s < nitems; s += 256) {
        int2 it = sorted[s];
        int p = it.y >> 7;
        stg_d[gbase[p] + (s - loff[p])] = it;
    }
}

// ============================================================
// dst-sort pass 2 (+ fused src-partition scatter)
// ============================================================
__global__ __launch_bounds__(256) void p2d_kernel(const int* __restrict__ gcur_d,
                                                  const int2* __restrict__ stg_d,
                                                  int* __restrict__ gcur_s,
                                                  int2* __restrict__ stg_s,
                                                  int* __restrict__ gcnt,
                                                  int* __restrict__ d_sr,
                                                  float* __restrict__ d_norm,
                                                  int* __restrict__ offs_d,
                                                  int* __restrict__ cnt_d) {
    __shared__ int2 sorted[CAPSTG];
    __shared__ int2 sorted2[CAPSTG];
    __shared__ int h[128], off[128], cur[128];
    __shared__ int sc[512];
    __shared__ int shist[NPART], sloff[NPART], scur[NPART], sgbase[NPART];
    __shared__ int kb;
    int p = blockIdx.x;
    int base = p * CAPSTG;
    int n = min(gcur_d[p] - base, CAPSTG);
    int t = threadIdx.x;
    if (t < 128) h[t] = 0;
    __syncthreads();
    for (int s = t; s < n; s += 256)
        atomicAdd(&h[stg_d[base + s].y & 127], 1);
    __syncthreads();
    if (t < 128) sc[t] = h[t];
    __syncthreads();
    scan128_incl(sc);
    if (t < 128) { int lo = t ? sc[t - 1] : 0; off[t] = lo; cur[t] = lo; }
    if (t == 0) kb = atomicAdd(&gcnt[0], n);
    __syncthreads();
    for (int s = t; s < n; s += 256) {
        int2 it = stg_d[base + s];
        int rk = atomicAdd(&cur[it.y & 127], 1);
        sorted[rk] = it;
    }
    __syncthreads();
    int kbase = kb;
    for (int s = t; s < n; s += 256) {
        int2 it = sorted[s];
        int key = it.y & 127;
        int r = it.x >> 16;
        int o = off[key], oe = o + h[key];
        int c = 0;
        for (int kk = o; kk < oe; ++kk)
            c += ((sorted[kk].x >> 16) == r);
        d_sr[kbase + s] = it.x;
        d_norm[kbase + s] = 1.0f / (float)c;
    }
    if (t < 128) {
        int node = (p << 7) + t;
        if (node < NNODES) { offs_d[node] = kbase + off[t]; cnt_d[node] = h[t]; }
    }
    // ---- fused src-partition scatter of (pk, k) ----
    for (int i = t; i < NPART; i += 256) shist[i] = 0;
    __syncthreads();
    for (int s = t; s < n; s += 256)
        atomicAdd(&shist[(sorted[s].x & 0xFFFF) >> 7], 1);
    __syncthreads();
    sc[t]       = (t < NPART) ? shist[t] : 0;
    sc[t + 256] = (t + 256 < NPART) ? shist[t + 256] : 0;
    __syncthreads();
    scan512_incl(sc);
    for (int pp = t; pp < NPART; pp += 256) {
        int lo = pp ? sc[pp - 1] : 0;
        sloff[pp] = lo;
        scur[pp] = lo;
        if (shist[pp]) sgbase[pp] = atomicAdd(&gcur_s[pp], shist[pp]);
    }
    __syncthreads();
    for (int s = t; s < n; s += 256) {
        int2 it = sorted[s];
        int rk = atomicAdd(&scur[(it.x & 0xFFFF) >> 7], 1);
        sorted2[rk] = make_int2(it.x, kbase + s);
    }
    __syncthreads();
    for (int s = t; s < n; s += 256) {
        int2 it = sorted2[s];
        int pp = (it.x & 0xFFFF) >> 7;
        stg_s[sgbase[pp] + (s - sloff[pp])] = it;
    }
}

// ============================================================
// src-sort pass 2: count-sort by src&127; emits sB/s_k, offs_s/cnt_s.
// ============================================================
__global__ __launch_bounds__(256) void p2s_kernel(const int* __restrict__ gcur_s,
                                                  const int2* __restrict__ stg_s,
                                                  int* __restrict__ gcnt,
                                                  int* __restrict__ sB,
                                                  int* __restrict__ s_k,
                                                  int* __restrict__ offs_s,
                                                  int* __restrict__ cnt_s) {
    __shared__ int2 sorted[CAPSTG];
    __shared__ int h[128], off[128], cur[128], sc[128];
    __shared__ int jb;
    int p = blockIdx.x;
    int base = p * CAPSTG;
    int n = min(gcur_s[p] - base, CAPSTG);
    int t = threadIdx.x;
    if (t < 128) h[t] = 0;
    __syncthreads();
    for (int s = t; s < n; s += 256)
        atomicAdd(&h[stg_s[base + s].x & 127], 1);
    __syncthreads();
    if (t < 128) sc[t] = h[t];
    __syncthreads();
    scan128_incl(sc);
    if (t < 128) { int lo = t ? sc[t - 1] : 0; off[t] = lo; cur[t] = lo; }
    if (t == 0) jb = atomicAdd(&gcnt[1], n);
    __syncthreads();
    for (int s = t; s < n; s += 256) {
        int2 it = stg_s[base + s];
        int rk = atomicAdd(&cur[it.x & 127], 1);
        sorted[rk] = it;
    }
    __syncthreads();
    int jbase = jb;
    for (int s = t; s < n; s += 256) {
        int2 it = sorted[s];
        sB[jbase + s]  = it.x;
        s_k[jbase + s] = it.y;
    }
    if (t < 128) {
        int node = (p << 7) + t;
        if (node < NNODES) { offs_s[node] = jbase + off[t]; cnt_s[node] = h[t]; }
    }
}

// ============================================================
// layer-1 messages: basis slices packed f16-over-b in LDS; comp rows
// pre-packed. f16 message written at dst-slot k (32B scattered row).
// ============================================================
__global__ __launch_bounds__(256) void msg1_lds(const float* __restrict__ basis1,
                                                const unsigned* __restrict__ comp_pk,
                                                const int* __restrict__ offs_s,
                                                const int* __restrict__ cnt_s,
                                                const int* __restrict__ sB,
                                                const int* __restrict__ s_k,
                                                unsigned* __restrict__ m1) {
    __shared__ unsigned bspk[GS * BSTR2];     // 8.3 KB
    __shared__ unsigned cpk[NREL * CROW2];    // 7.2 KB
    int src0 = blockIdx.x * GS;
    int t = threadIdx.x;
    for (int i = t; i < (NREL * CROW2) / 4; i += 256)
        ((uint4*)cpk)[i] = ((const uint4*)comp_pk)[i];
    for (int i4 = t; i4 < 15 * 32; i4 += 256) {
        int b2 = i4 >> 5;
        int w  = i4 & 31;
        const float4* bp = (const float4*)basis1;
        float4 a = bp[(size_t)(2 * b2)     * (NNODES * 4) + (size_t)src0 * 4 + w];
        float4 b = bp[(size_t)(2 * b2 + 1) * (NNODES * 4) + (size_t)src0 * 4 + w];
        int s = w >> 2, q = w & 3;
        uint4 o;
        o.x = pk2(a.x, b.x);
        o.y = pk2(a.y, b.y);
        o.z = pk2(a.z, b.z);
        o.w = pk2(a.w, b.w);
        *((uint4*)(bspk + s * BSTR2 + b2 * 16 + q * 4)) = o;
    }
    __syncthreads();
    int n0 = offs_s[src0];
    int lastS = src0 + GS - 1;
    int n1 = offs_s[lastS] + cnt_s[lastS];
    for (int ii = n0 * 4 + t; ii < n1 * 4; ii += 256) {
        int j = ii >> 2;
        int q = ii & 3;
        int pk = sB[j];
        int k  = s_k[j];
        int src = pk & 0xFFFF;
        int r   = pk >> 16;
        const uint4* crow = (const uint4*)(cpk + r * CROW2);
        uint4 c0 = crow[0], c1 = crow[1], c2 = crow[2], c3 = crow[3];
        const unsigned* bw = bspk + (src - src0) * BSTR2 + q * 4;
        float a0 = 0.f, a1 = 0.f, a2 = 0.f, a3 = 0.f;
#define MSG1_STEP(B2, CB) { \
        uint4 v = *((const uint4*)(bw + (B2) * 16)); \
        a0 = fd2(v.x, (CB), a0); \
        a1 = fd2(v.y, (CB), a1); \
        a2 = fd2(v.z, (CB), a2); \
        a3 = fd2(v.w, (CB), a3); }
        MSG1_STEP(0,  c0.x) MSG1_STEP(1,  c0.y) MSG1_STEP(2,  c0.z) MSG1_STEP(3,  c0.w)
        MSG1_STEP(4,  c1.x) MSG1_STEP(5,  c1.y) MSG1_STEP(6,  c1.z) MSG1_STEP(7,  c1.w)
        MSG1_STEP(8,  c2.x) MSG1_STEP(9,  c2.y) MSG1_STEP(10, c2.z) MSG1_STEP(11, c2.w)
        MSG1_STEP(12, c3.x) MSG1_STEP(13, c3.y) MSG1_STEP(14, c3.z)
#undef MSG1_STEP
        ((uint2*)m1)[(size_t)k * 4 + q] = make_uint2(pk2(a0, a1), pk2(a2, a3));
    }
}

// ============================================================
// layer-1 gather: thread per (dst, h-quad); m1 f16, dst-ordered ->
// sequential uint2 reads; fuses norm + root1 + bias1 + relu.
// Writes h (f32, for gather2 root2 term) and h16 (f16, for msg2).
// ============================================================
__global__ __launch_bounds__(256) void gather1_flat(const unsigned* __restrict__ m1,
                                                    const float* __restrict__ d_norm,
                                                    const int* __restrict__ offs_d,
                                                    const int* __restrict__ cnt_d,
                                                    const float* __restrict__ root1,
                                                    const float* __restrict__ bias1,
                                                    float* __restrict__ h,
                                                    unsigned* __restrict__ h16) {
    int idx = blockIdx.x * blockDim.x + threadIdx.x;
    if (idx >= NNODES * 4) return;
    int dst = idx >> 2;
    int q   = idx & 3;
    int k0 = offs_d[dst];
    int k1 = k0 + cnt_d[dst];
    float4 acc = make_float4(0.f, 0.f, 0.f, 0.f);
    for (int k = k0; k < k1; ++k) {
        uint2 v = ((const uint2*)m1)[(size_t)k * 4 + q];
        float nm = d_norm[k];
        h2 x = uph(v.x), y = uph(v.y);
        acc.x = fmaf(nm, (float)x.x, acc.x);
        acc.y = fmaf(nm, (float)x.y, acc.y);
        acc.z = fmaf(nm, (float)y.x, acc.z);
        acc.w = fmaf(nm, (float)y.y, acc.w);
    }
    float4 rt = ((const float4*)root1)[idx];
    float4 bi = ((const float4*)bias1)[q];
    float4 o;
    o.x = fmaxf(acc.x + rt.x + bi.x, 0.f);
    o.y = fmaxf(acc.y + rt.y + bi.y, 0.f);
    o.z = fmaxf(acc.z + rt.z + bi.z, 0.f);
    o.w = fmaxf(acc.w + rt.w + bi.w, 0.f);
    ((float4*)h)[idx] = o;
    ((uint2*)h16)[idx] = make_uint2(pk2(o.x, o.y), pk2(o.z, o.w));
}

// ============================================================
// W2 packed f16: w2pk[(r*8+c)*8 + p] = (W2[r][2p][c], W2[r][2p+1][c]);
// r2t[c][hh] = root2[hh][c].
// ============================================================
__global__ __launch_bounds__(256) void w2pk_kernel(const float* __restrict__ basis2,
                                                   const float* __restrict__ comp2,
                                                   const float* __restrict__ root2,
                                                   unsigned* __restrict__ w2pk,
                                                   float* __restrict__ r2t) {
    int i = blockIdx.x * blockDim.x + threadIdx.x;
    if (i >= NREL * NCLS * 8) return;
    int r = i >> 6;
    int c = (i >> 3) & (NCLS - 1);
    int p = i & 7;
    float a0 = 0.f, a1 = 0.f;
#pragma unroll
    for (int b = 0; b < NBASIS; ++b) {
        float cb = comp2[r * NBASIS + b];
        a0 = fmaf(cb, basis2[(b * HDIM + 2 * p)     * NCLS + c], a0);
        a1 = fmaf(cb, basis2[(b * HDIM + 2 * p + 1) * NCLS + c], a1);
    }
    w2pk[i] = pk2(a0, a1);
    if (i < HDIM * NCLS) {
        int c2 = i >> 4;
        int k2 = i & (HDIM - 1);
        r2t[i] = root2[k2 * NCLS + c2];
    }
}

// ============================================================
// layer-2 messages, class-pair threads: thread per (edge-slot k, cpair).
// Computes classes 2cp and 2cp+1; m2 stored as packed f16 pairs
// (m2pk[k*4+cp]) -> half the m2 traffic, half the redundant loads.
// ============================================================
__global__ __launch_bounds__(256) void msg2_kernel(const unsigned* __restrict__ h16,
                                                   const unsigned* __restrict__ w2pk,
                                                   const int* __restrict__ d_sr,
                                                   const float* __restrict__ d_norm,
                                                   unsigned* __restrict__ m2pk) {
    int idx = blockIdx.x * blockDim.x + threadIdx.x;   // NEDGE*4 = 3,200,000 exact
    int k  = idx >> 2;
    int cp = idx & 3;
    int pk = d_sr[k];
    float nm = d_norm[k];
    int src = pk & 0xFFFF;
    int r   = pk >> 16;
    const uint4* __restrict__ hp = (const uint4*)(h16 + src * 8);
    uint4 h0 = hp[0], h1 = hp[1];
    const uint4* __restrict__ w0p = (const uint4*)(w2pk + (r * NCLS + 2 * cp) * 8);
    const uint4* __restrict__ w1p = (const uint4*)(w2pk + (r * NCLS + 2 * cp + 1) * 8);
    uint4 wa0 = w0p[0], wa1 = w0p[1];
    uint4 wb0 = w1p[0], wb1 = w1p[1];
    float a0 = 0.f, a1 = 0.f;
    a0 = fd2(h0.x, wa0.x, a0);  a1 = fd2(h0.x, wb0.x, a1);
    a0 = fd2(h0.y, wa0.y, a0);  a1 = fd2(h0.y, wb0.y, a1);
    a0 = fd2(h0.z, wa0.z, a0);  a1 = fd2(h0.z, wb0.z, a1);
    a0 = fd2(h0.w, wa0.w, a0);  a1 = fd2(h0.w, wb0.w, a1);
    a0 = fd2(h1.x, wa1.x, a0);  a1 = fd2(h1.x, wb1.x, a1);
    a0 = fd2(h1.y, wa1.y, a0);  a1 = fd2(h1.y, wb1.y, a1);
    a0 = fd2(h1.z, wa1.z, a0);  a1 = fd2(h1.z, wb1.z, a1);
    a0 = fd2(h1.w, wa1.w, a0);  a1 = fd2(h1.w, wb1.w, a1);
    m2pk[idx] = pk2(nm * a0, nm * a1);
}

// ============================================================
// layer-2 gather, class-pair threads: thread per (dst, cpair);
// sequential m2pk reads (16B per k per 4-lane group); fused
// root2 + bias2 + log_softmax (4-lane shfl over pairs).
// ============================================================
__global__ __launch_bounds__(256) void gather2_kernel(const unsigned* __restrict__ m2pk,
                                                      const float* __restrict__ h,
                                                      const float* __restrict__ r2t,
                                                      const int* __restrict__ offs_d,
                                                      const int* __restrict__ cnt_d,
                                                      const float* __restrict__ bias2,
                                                      float* __restrict__ out) {
    int idx = blockIdx.x * blockDim.x + threadIdx.x;
    if (idx >= NNODES * 4) return;
    int dst = idx >> 2;
    int cp  = idx & 3;
    int k0 = offs_d[dst];
    int k1 = k0 + cnt_d[dst];
    float s0 = 0.f, s1 = 0.f;
    for (int k = k0; k < k1; ++k) {
        h2 v = uph(m2pk[k * 4 + cp]);
        s0 += (float)v.x;
        s1 += (float)v.y;
    }
    int c0 = 2 * cp, c1 = 2 * cp + 1;
    float v0 = s0 + bias2[c0];
    float v1 = s1 + bias2[c1];
    const float4* __restrict__ hd = (const float4*)h + dst * 4;
    const float4* __restrict__ r0 = (const float4*)r2t + c0 * 4;
    const float4* __restrict__ r1 = (const float4*)r2t + c1 * 4;
#pragma unroll
    for (int qq = 0; qq < 4; ++qq) {
        float4 hv = hd[qq];
        float4 ra = r0[qq];
        float4 rb = r1[qq];
        v0 = fmaf(hv.x, ra.x, v0); v1 = fmaf(hv.x, rb.x, v1);
        v0 = fmaf(hv.y, ra.y, v0); v1 = fmaf(hv.y, rb.y, v1);
        v0 = fmaf(hv.z, ra.z, v0); v1 = fmaf(hv.z, rb.z, v1);
        v0 = fmaf(hv.w, ra.w, v0); v1 = fmaf(hv.w, rb.w, v1);
    }
    float mx = fmaxf(v0, v1);
    mx = fmaxf(mx, __shfl_xor(mx, 1));
    mx = fmaxf(mx, __shfl_xor(mx, 2));
    float s = expf(v0 - mx) + expf(v1 - mx);
    s += __shfl_xor(s, 1);
    s += __shfl_xor(s, 2);
    float ls = logf(s);
    ((float2*)out)[idx] = make_float2(v0 - mx - ls, v1 - mx - ls);
}

// ============================================================
// fallback (flat atomic path; needs ~23.3 MB)
// ============================================================
__global__ __launch_bounds__(256) void degcnt_fb(const int* __restrict__ ei,
                                                 const int* __restrict__ et,
                                                 int* __restrict__ deg) {
    int e = blockIdx.x * blockDim.x + threadIdx.x;
    if (e >= NEDGE) return;
    atomicAdd(&deg[ei[NEDGE + e] * NREL + et[e]], 1);
}

__global__ __launch_bounds__(256) void layer1_flat(const int* __restrict__ ei,
                                                   const int* __restrict__ et,
                                                   const float* __restrict__ basis1,
                                                   const float* __restrict__ comp1,
                                                   const int* __restrict__ deg,
                                                   float* __restrict__ h) {
    long long idx = (long long)blockIdx.x * blockDim.x + threadIdx.x;
    if (idx >= (long long)NEDGE * HDIM) return;
    int e  = (int)(idx >> 4);
    int hh = (int)(idx & (HDIM - 1));
    int src = ei[e];
    int dst = ei[NEDGE + e];
    int r   = et[e];
    float norm = 1.0f / (float)deg[dst * NREL + r];
    const float* __restrict__ cp = comp1 + r * NBASIS;
    float acc = 0.f;
#pragma unroll
    for (int b = 0; b < NBASIS; ++b)
        acc += cp[b] * basis1[(b * NNODES + src) * HDIM + hh];
    atomicAdd(&h[dst * HDIM + hh], norm * acc);
}

__global__ __launch_bounds__(256) void relu_kernel(float* __restrict__ h,
                                                   const float* __restrict__ root1,
                                                   const float* __restrict__ bias1) {
    int i = blockIdx.x * blockDim.x + threadIdx.x;
    if (i >= NNODES * HDIM) return;
    float v = h[i] + root1[i] + bias1[i & (HDIM - 1)];
    h[i] = v > 0.f ? v : 0.f;
}

__global__ __launch_bounds__(256) void w2_kernel_fb(const float* __restrict__ basis2,
                                                    const float* __restrict__ comp2,
                                                    const float* __restrict__ root2,
                                                    float* __restrict__ w2t,
                                                    float* __restrict__ r2t) {
    int i = blockIdx.x * blockDim.x + threadIdx.x;
    if (i >= NREL * HDIM * NCLS) return;
    int kk = i & (HDIM - 1);
    int c  = (i >> 4) & (NCLS - 1);
    int r  = i >> 7;
    float acc = 0.f;
#pragma unroll
    for (int b = 0; b < NBASIS; ++b)
        acc += comp2[r * NBASIS + b] * basis2[(b * HDIM + kk) * NCLS + c];
    w2t[i] = acc;
    if (i < HDIM * NCLS) {
        int c2 = i >> 4;
        int k2 = i & (HDIM - 1);
        r2t[i] = root2[k2 * NCLS + c2];
    }
}

__global__ __launch_bounds__(256) void layer2_flat(const int* __restrict__ ei,
                                                   const int* __restrict__ et,
                                                   const float* __restrict__ h,
                                                   const float* __restrict__ w2t,
                                                   const int* __restrict__ deg,
                                                   float* __restrict__ out_tmp) {
    long long idx = (long long)blockIdx.x * blockDim.x + threadIdx.x;
    if (idx >= (long long)NEDGE * NCLS) return;
    int e = (int)(idx >> 3);
    int c = (int)(idx & (NCLS - 1));
    int src = ei[e];
    int dst = ei[NEDGE + e];
    int r   = et[e];
    float norm = 1.0f / (float)deg[dst * NREL + r];
    const float4* __restrict__ hp = (const float4*)h + src * 4;
    const float4* __restrict__ wp = (const float4*)w2t + (r * NCLS + c) * 4;
    float a = 0.f;
#pragma unroll
    for (int qq = 0; qq < 4; ++qq) {
        float4 hv = hp[qq];
        float4 wv = wp[qq];
        a = fmaf(hv.x, wv.x, a);
        a = fmaf(hv.y, wv.y, a);
        a = fmaf(hv.z, wv.z, a);
        a = fmaf(hv.w, wv.w, a);
    }
    atomicAdd(&out_tmp[dst * NCLS + c], norm * a);
}

__global__ __launch_bounds__(256) void final_kernel(const float* __restrict__ out_tmp,
                                                    const float* __restrict__ h,
                                                    const float* __restrict__ root2,
                                                    const float* __restrict__ bias2,
                                                    float* __restrict__ out) {
    int n = blockIdx.x * blockDim.x + threadIdx.x;
    if (n >= NNODES) return;
    float hv[HDIM];
#pragma unroll
    for (int i = 0; i < HDIM; ++i) hv[i] = h[n * HDIM + i];
    float v[NCLS];
    float mx = -1e30f;
#pragma unroll
    for (int c = 0; c < NCLS; ++c) {
        float acc = out_tmp[n * NCLS + c] + bias2[c];
#pragma unroll
        for (int i = 0; i < HDIM; ++i) acc += hv[i] * root2[i * NCLS + c];
        v[c] = acc;
        mx = fmaxf(mx, acc);
    }
    float s = 0.f;
#pragma unroll
    for (int c = 0; c < NCLS; ++c) s += expf(v[c] - mx);
    float ls = logf(s);
#pragma unroll
    for (int c = 0; c < NCLS; ++c) out[n * NCLS + c] = v[c] - mx - ls;
}

extern "C" void kernel_launch(void* const* d_in, const int* in_sizes, int n_in,
                              void* d_out, int out_size, void* d_ws, size_t ws_size,
                              hipStream_t stream) {
    const int*   ei     = (const int*)d_in[0];
    const int*   et     = (const int*)d_in[1];
    const float* basis1 = (const float*)d_in[2];
    const float* comp1  = (const float*)d_in[3];
    const float* root1  = (const float*)d_in[4];
    const float* bias1  = (const float*)d_in[5];
    const float* basis2 = (const float*)d_in[6];
    const float* comp2  = (const float*)d_in[7];
    const float* root2  = (const float*)d_in[8];
    const float* bias2  = (const float*)d_in[9];
    float* out = (float*)d_out;

    // ---------- primary layout (4-byte words; vectors at aligned offsets) ----------
    int*      gcur_s  = (int*)d_ws;                            // NPART
    int*      gcur_d  = gcur_s + NPART;                        // NPART
    int*      gcnt    = gcur_d + NPART;                        // 4
    unsigned* comp_pk = (unsigned*)(gcnt + 4);                 // NREL*CROW2 = 1800
    int2*  stg_d  = (int2*)(comp_pk + NREL * CROW2);           // NPART*CAPSTG int2
    int2*  stg_s  = stg_d + (size_t)NPART * CAPSTG;            // NPART*CAPSTG int2
    int*   d_sr   = (int*)(stg_s + (size_t)NPART * CAPSTG);    // E
    float* d_norm = (float*)(d_sr + NEDGE);                    // E
    int*   sB     = (int*)(d_norm + NEDGE);                    // E
    int*   s_k    = sB + NEDGE;                                // E
    int*   offs_s = s_k + NEDGE;                               // N
    int*   cnt_s  = offs_s + NNODES;                           // N
    int*   offs_d = cnt_s + NNODES;                            // N
    int*   cnt_d  = offs_d + NNODES;                           // N
    unsigned* m1  = (unsigned*)(cnt_d + NNODES);               // E*8 words (E*16 f16)
    unsigned* m2pk = m1;                                       // E*4 words aliases (m1 dead)
    float* h      = (float*)(m1 + (size_t)NEDGE * 8);          // N*16 f32
    unsigned* h16 = (unsigned*)(h + (size_t)NNODES * HDIM);    // N*8 u32 (16 f16)
    unsigned* w2pk = h16 + (size_t)NNODES * 8;                 // R*C*8 u32
    float* r2t    = (float*)(w2pk + (size_t)NREL * NCLS * 8);  // H*C
    size_t total_words = 2 * (size_t)NPART + 4 + NREL * CROW2 +
                         4 * (size_t)NPART * CAPSTG +
                         4 * (size_t)NEDGE + 4 * (size_t)NNODES +
                         (size_t)NEDGE * 8 + (size_t)NNODES * HDIM +
                         (size_t)NNODES * 8 + (size_t)NREL * NCLS * 8 + HDIM * NCLS;

    if (ws_size >= total_words * sizeof(float)) {
        initc_kernel<<<8, 256, 0, stream>>>(gcur_s, gcur_d, gcnt, comp1, comp_pk);
        p1d_kernel<<<P1BLK, 256, 0, stream>>>(ei, et, gcur_d, stg_d);
        p2d_kernel<<<NPART - 1, 256, 0, stream>>>(gcur_d, stg_d, gcur_s, stg_s, gcnt,
                                                  d_sr, d_norm, offs_d, cnt_d);
        p2s_kernel<<<NPART - 1, 256, 0, stream>>>(gcur_s, stg_s, gcnt, sB, s_k, offs_s, cnt_s);

        msg1_lds<<<NNODES / GS, 256, 0, stream>>>(basis1, comp_pk, offs_s, cnt_s, sB, s_k, m1);
        gather1_flat<<<(NNODES * 4 + 255) / 256, 256, 0, stream>>>(
            m1, d_norm, offs_d, cnt_d, root1, bias1, h, h16);
        w2pk_kernel<<<(NREL * NCLS * 8 + 255) / 256, 256, 0, stream>>>(basis2, comp2, root2,
                                                                       w2pk, r2t);
        msg2_kernel<<<(NEDGE * 4) / 256, 256, 0, stream>>>(h16, w2pk, d_sr, d_norm, m2pk);
        gather2_kernel<<<(NNODES * 4 + 255) / 256, 256, 0, stream>>>(
            m2pk, h, r2t, offs_d, cnt_d, bias2, out);
        return;
    }

    // ---------- fallback: flat atomic path (~23.3 MB) ----------
    {
        int*   deg_f   = (int*)d_ws;                               // N*R  (zero)
        float* h_f     = (float*)(deg_f + (size_t)NNODES * NREL);  // N*H  (zero)
        float* out_tmp = h_f + (size_t)NNODES * HDIM;              // N*C  (zero)
        size_t zw = (size_t)NNODES * NREL + NNODES * HDIM + NNODES * NCLS;
        float* w2t_f   = out_tmp + (size_t)NNODES * NCLS;          // R*H*C
        float* r2t_f   = w2t_f + (size_t)NREL * HDIM * NCLS;       // H*C

        (void)hipMemsetAsync(d_ws, 0, zw * sizeof(float), stream);
        degcnt_fb<<<(NEDGE + 255) / 256, 256, 0, stream>>>(ei, et, deg_f);
        layer1_flat<<<((size_t)NEDGE * HDIM + 255) / 256, 256, 0, stream>>>(
            ei, et, basis1, comp1, deg_f, h_f);
        relu_kernel<<<(NNODES * HDIM + 255) / 256, 256, 0, stream>>>(h_f, root1, bias1);
        w2_kernel_fb<<<(NREL * HDIM * NCLS + 255) / 256, 256, 0, stream>>>(basis2, comp2, root2,
                                                                           w2t_f, r2t_f);
        layer2_flat<<<((size_t)NEDGE * NCLS + 255) / 256, 256, 0, stream>>>(
            ei, et, h_f, w2t_f, deg_f, out_tmp);
        final_kernel<<<(NNODES + 255) / 256, 256, 0, stream>>>(out_tmp, h_f, root2, bias2, out);
    }
}